// Round 1
// baseline (553.019 us; speedup 1.0000x reference)
//
#include <hip/hip_runtime.h>
#include <hip/hip_bf16.h>

#define NNODES 50000
#define NEDGES 800000
#define EB 1024          // edge grid: 4 blocks/CU resident
#define SCAN_BLOCKS 196  // ceil(50000/256)
#define TRN_BLOCKS 448   // 114688 weight elems / 256

typedef short bf16x8 __attribute__((ext_vector_type(8)));
typedef float f32x4 __attribute__((ext_vector_type(4)));
typedef unsigned short u16;
typedef unsigned int u32;

__device__ __forceinline__ u16 f2bf(float f) {
    __hip_bfloat16 b = __float2bfloat16(f);
    return *reinterpret_cast<u16*>(&b);
}
__device__ __forceinline__ float bf2f(u16 v) {
    u32 u = ((u32)v) << 16;
    return __uint_as_float(u);
}
__device__ __forceinline__ u32 pack2(float a, float b) {
    __hip_bfloat162 t = __float22bfloat162_rn(float2{a, b});
    return *reinterpret_cast<u32*>(&t);
}
// silu without IEEE divide: x * rcp(1 + 2^(-x*log2e))
__device__ __forceinline__ float fast_silu(float x) {
    float e = __builtin_amdgcn_exp2f(-1.442695040888963f * x);
    return x * __builtin_amdgcn_rcpf(1.0f + e);
}
__device__ __forceinline__ bf16x8 ld8(const u16* p) {
    return *(const bf16x8*)p;
}
__device__ __forceinline__ f32x4 mfma16(bf16x8 a, bf16x8 b, f32x4 c) {
    return __builtin_amdgcn_mfma_f32_16x16x32_bf16(a, b, c, 0, 0, 0);
}
// Barrier that drains LDS ops only — leaves vector-memory prefetch loads
// (register destinations) in flight across the barrier. Safe here because
// the only global writes in edge_kernel are atomics no one re-reads.
__device__ __forceinline__ void bar_lds() {
    asm volatile("s_waitcnt lgkmcnt(0)\n\ts_barrier" ::: "memory");
}

// ---- prep: 5 weight transposes (fp32->bf16) + receiver histogram ----
__global__ void prep_kernel(const float* __restrict__ eW1, const float* __restrict__ eW2,
                            const float* __restrict__ pW1, const float* __restrict__ nW1,
                            const float* __restrict__ nW2,
                            u16* __restrict__ eW1T, u16* __restrict__ eW2T,
                            u16* __restrict__ pW1T, u16* __restrict__ nW1T,
                            u16* __restrict__ nW2T,
                            const int* __restrict__ rcv, int* __restrict__ counts) {
    int b = blockIdx.x;
    if (b < TRN_BLOCKS) {
        int i = b * 256 + threadIdx.x;
        const float* src; u16* dst; int K;
        if (i < 32768)      { src = eW1; dst = eW1T; K = 256; }
        else if (i < 49152) { src = eW2; dst = eW2T; K = 128; i -= 32768; }
        else if (i < 65536) { src = pW1; dst = pW1T; K = 128; i -= 49152; }
        else if (i < 98304) { src = nW1; dst = nW1T; K = 256; i -= 65536; }
        else                { src = nW2; dst = nW2T; K = 128; i -= 98304; }
        int n = i / K, k = i - n * K;
        dst[i] = f2bf(src[k * 128 + n]);
    } else {
        int e = (b - TRN_BLOCKS) * 256 + threadIdx.x;
        if (e < NEDGES) atomicAdd(&counts[rcv[e]], 1);
    }
}

// ---- P precompute: P[n] = [h@eW1a + eb1/2 | h@eW1b + eb1/2 | h@nW1a] (bf16) ----
__global__ __launch_bounds__(256) void gemm_p(
    const float* __restrict__ h, const u16* __restrict__ eW1T,
    const u16* __restrict__ nW1T, const float* __restrict__ eb1,
    u16* __restrict__ P)
{
    const int tid  = threadIdx.x;
    const int w    = tid >> 6;
    const int lane = tid & 63;
    const int m    = lane & 15;
    const int quad = lane >> 4;
    const int ksub = quad * 8;

    bf16x8 bw[4][6];
    float bias[6];
    #pragma unroll
    for (int cc = 0; cc < 6; cc++) {
        int C = 96 * w + 16 * cc + m;
        const u16* bp;
        if (C < 128)      { bp = eW1T + C * 256;               bias[cc] = 0.5f * eb1[C]; }
        else if (C < 256) { bp = eW1T + (C - 128) * 256 + 128; bias[cc] = 0.5f * eb1[C - 128]; }
        else              { bp = nW1T + (C - 256) * 256;       bias[cc] = 0.f; }
        #pragma unroll
        for (int t = 0; t < 4; t++) bw[t][cc] = ld8(bp + t * 32 + ksub);
    }
    const int base = blockIdx.x * 64;
    #pragma unroll
    for (int mt = 0; mt < 4; mt++) {
        int nm = base + mt * 16 + m;
        if (nm >= NNODES) nm = NNODES - 1;
        bf16x8 afr[4];
        #pragma unroll
        for (int t = 0; t < 4; t++) {
            const float* ap = h + (size_t)nm * 128 + t * 32 + ksub;
            f32x4 lo = *(const f32x4*)ap;
            f32x4 hi = *(const f32x4*)(ap + 4);
            #pragma unroll
            for (int j = 0; j < 4; j++) {
                afr[t][j]     = (short)f2bf(lo[j]);
                afr[t][4 + j] = (short)f2bf(hi[j]);
            }
        }
        f32x4 acc[6];
        #pragma unroll
        for (int cc = 0; cc < 6; cc++) acc[cc] = (f32x4){0,0,0,0};
        #pragma unroll
        for (int t = 0; t < 4; t++)
            #pragma unroll
            for (int cc = 0; cc < 6; cc++)
                acc[cc] = mfma16(afr[t], bw[t][cc], acc[cc]);
        #pragma unroll
        for (int cc = 0; cc < 6; cc++) {
            int C = 96 * w + 16 * cc + m;
            #pragma unroll
            for (int r = 0; r < 4; r++) {
                int nr = base + mt * 16 + quad * 4 + r;
                if (nr < NNODES) P[(size_t)nr * 384 + C] = f2bf(acc[cc][r] + bias[cc]);
            }
        }
    }
}

// ---- scan chain ----
__global__ void scan1(const int* __restrict__ counts, int* __restrict__ excl,
                      int* __restrict__ blkSum) {
    __shared__ int tmp[256];
    int tx = threadIdx.x;
    int i = blockIdx.x * 256 + tx;
    int v = (i < NNODES) ? counts[i] : 0;
    tmp[tx] = v;
    __syncthreads();
    for (int off = 1; off < 256; off <<= 1) {
        int t = (tx >= off) ? tmp[tx - off] : 0;
        __syncthreads();
        tmp[tx] += t;
        __syncthreads();
    }
    if (i < NNODES) excl[i] = tmp[tx] - v;
    if (tx == 255) blkSum[blockIdx.x] = tmp[255];
}
__global__ void scan2(const int* __restrict__ blkSum, int* __restrict__ blkOff) {
    __shared__ int tmp[256];
    int tx = threadIdx.x;
    int v = (tx < SCAN_BLOCKS) ? blkSum[tx] : 0;
    tmp[tx] = v;
    __syncthreads();
    for (int off = 1; off < 256; off <<= 1) {
        int t = (tx >= off) ? tmp[tx - off] : 0;
        __syncthreads();
        tmp[tx] += t;
        __syncthreads();
    }
    if (tx < SCAN_BLOCKS) blkOff[tx] = tmp[tx] - v;
}
__global__ void scan3(const int* __restrict__ excl, const int* __restrict__ blkOff,
                      int* __restrict__ cursor) {
    int i = blockIdx.x * 256 + threadIdx.x;
    if (i < NNODES) cursor[i] = excl[i] + blkOff[blockIdx.x];
}
__global__ void scatter_kernel(const int* __restrict__ rcv, int* __restrict__ cursor,
                               int* __restrict__ perm) {
    int e = blockIdx.x * 256 + threadIdx.x;
    if (e < NEDGES) {
        int p = atomicAdd(&cursor[rcv[e]], 1);
        perm[p] = e;
    }
}

struct __align__(16) EdgeLds {
    u16   m1[64 * 136];       // XOR-swizzled 8-col chunks
    u16   msg[64 * 136];
    float diff[64][4];
    float pcpart[4][64];
    float wlast[128];
    int   sndloc[64];
    int   rcvloc[64];
    unsigned long long bmap;  // bit i = (rcv[i] != rcv[i-1]) within tile
};   // ~38 KB -> 4 blocks/CU

__global__ __launch_bounds__(256, 4) void edge_kernel(
    const u16* __restrict__ P, const float* __restrict__ pos,
    const int* __restrict__ snd, const int* __restrict__ rcv,
    const int* __restrict__ perm,
    const float* __restrict__ eW1last,
    const u16* __restrict__ eW2T, const float* __restrict__ eb2,
    const u16* __restrict__ pW1T, const float* __restrict__ pb1,
    const float* __restrict__ pW2,
    float* __restrict__ agg, float* __restrict__ posacc)
{
    __shared__ EdgeLds S;
    const int tid  = threadIdx.x;
    const int w    = tid >> 6;
    const int lane = tid & 63;
    const int m    = lane & 15;
    const int quad = lane >> 4;
    const int ksub = quad * 8;

    bf16x8 bw2[4][2], bp1[4][2];
    float b2v[2], pb1v[2], pw2v[2];
    #pragma unroll
    for (int cc = 0; cc < 2; cc++) {
        int col = (2 * w + cc) * 16 + m;
        #pragma unroll
        for (int t = 0; t < 4; t++) {
            bw2[t][cc] = ld8(eW2T + col * 128 + t * 32 + ksub);
            bp1[t][cc] = ld8(pW1T + col * 128 + t * 32 + ksub);
        }
        b2v[cc]  = eb2[col];
        pb1v[cc] = pb1[col];
        pw2v[cc] = pW2[col];
    }
    if (tid < 128) S.wlast[tid] = eW1last[tid];

    const int stride = gridDim.x * 64;

    // ---- prologue: prefetch tile 0 into registers ----
    int s_n, r_n;
    float ps_n[3], pr_n[3];
    bf16x8 pa_n[4], pb_n[4];
    {
        int eg = perm[blockIdx.x * 64 + lane];
        s_n = snd[eg]; r_n = rcv[eg];
        #pragma unroll
        for (int c = 0; c < 3; c++) { ps_n[c] = pos[s_n * 3 + c]; pr_n[c] = pos[r_n * 3 + c]; }
        #pragma unroll
        for (int t = 0; t < 4; t++) {
            pa_n[t] = ld8(P + (size_t)s_n * 384 + w * 32 + t * 8);
            pb_n[t] = ld8(P + (size_t)r_n * 384 + 128 + w * 32 + t * 8);
        }
    }

    for (int base = blockIdx.x * 64; base < NEDGES; base += stride) {
        int nbase = base + stride;
        int pfb = (nbase < NEDGES) ? nbase : base;   // last iter: dummy (discarded)

        bar_lds();   // X1: protect S.* reuse vs previous tile's consumers
        // current tile state = prefetched registers
        const int s = s_n, r = r_n;
        const float d0 = ps_n[0] - pr_n[0];
        const float d1 = ps_n[1] - pr_n[1];
        const float d2 = ps_n[2] - pr_n[2];
        const float rad = d0 * d0 + d1 * d1 + d2 * d2;
        bf16x8 pa[4], pb[4];
        #pragma unroll
        for (int t = 0; t < 4; t++) { pa[t] = pa_n[t]; pb[t] = pb_n[t]; }

        // prefetch stage 1: next tile's perm entries (no dependencies)
        int eg_n = perm[pfb + lane];

        if (tid < 64) {
            S.sndloc[tid] = s; S.rcvloc[tid] = r;
            S.diff[tid][0] = d0; S.diff[tid][1] = d1; S.diff[tid][2] = d2;
            int pv = __shfl_up(r, 1);
            unsigned long long bm = __ballot(lane > 0 && r != pv);
            if (tid == 0) S.bmap = bm;
        }

        // ---- layer1: m1 = silu(Pa[s] + Pb[r] + rad*wlast) — all inputs in regs ----
        {
            const int sw = lane >> 3;
            #pragma unroll
            for (int k = 0; k < 4; k++) {
                bf16x8 va = pa[k];
                bf16x8 vb = pb[k];
                u32 pk[4];
                #pragma unroll
                for (int jj = 0; jj < 4; jj++) {
                    int col = w * 32 + k * 8 + jj * 2;
                    float2 wl = *(const float2*)&S.wlast[col];
                    float v0 = bf2f((u16)va[jj * 2])     + bf2f((u16)vb[jj * 2])     + rad * wl.x;
                    float v1 = bf2f((u16)va[jj * 2 + 1]) + bf2f((u16)vb[jj * 2 + 1]) + rad * wl.y;
                    pk[jj] = pack2(fast_silu(v0), fast_silu(v1));
                }
                int chunk = (w * 4 + k) ^ sw;
                *(uint4*)&S.m1[lane * 136 + chunk * 8] =
                    make_uint4(pk[0], pk[1], pk[2], pk[3]);
            }
        }

        // prefetch stage 2: next snd/rcv (eg_n landed during layer1)
        s_n = snd[eg_n]; r_n = rcv[eg_n];

        bar_lds();   // X3
        // ---- layer2: msg = silu(m1 @ eW2 + b2) ----
        #pragma unroll
        for (int mt = 0; mt < 4; mt++) {
            const int rs = mt * 2 + (m >> 3);
            const int row = mt * 16 + m;
            f32x4 acc0 = (f32x4){0,0,0,0}, acc1 = (f32x4){0,0,0,0};
            #pragma unroll
            for (int t = 0; t < 4; t++) {
                bf16x8 a = *(const bf16x8*)&S.m1[row * 136 + ((t * 4 + quad) ^ rs) * 8];
                acc0 = mfma16(a, bw2[t][0], acc0);
                acc1 = mfma16(a, bw2[t][1], acc1);
            }
            #pragma unroll
            for (int cc = 0; cc < 2; cc++) {
                f32x4 acc = cc ? acc1 : acc0;
                int col = (2 * w + cc) * 16 + m;
                #pragma unroll
                for (int rr = 0; rr < 4; rr++) {
                    int orow = mt * 16 + quad * 4 + rr;
                    S.msg[orow * 136 + col] = f2bf(fast_silu(acc[rr] + b2v[cc]));
                }
            }
        }

        // prefetch stage 3: next pos + P fragments (s_n/r_n landed during layer2);
        // these loads stay in flight across X4/X5/X1 and land during pos-head/walk
        #pragma unroll
        for (int c = 0; c < 3; c++) { ps_n[c] = pos[s_n * 3 + c]; pr_n[c] = pos[r_n * 3 + c]; }
        #pragma unroll
        for (int t = 0; t < 4; t++) {
            pa_n[t] = ld8(P + (size_t)s_n * 384 + w * 32 + t * 8);
            pb_n[t] = ld8(P + (size_t)r_n * 384 + 128 + w * 32 + t * 8);
        }

        bar_lds();   // X4
        // ---- pos head: pc = silu(msg @ pW1 + pb1) @ pW2 (per-wave partials) ----
        #pragma unroll
        for (int mt = 0; mt < 4; mt++) {
            f32x4 acc0 = (f32x4){0,0,0,0}, acc1 = (f32x4){0,0,0,0};
            #pragma unroll
            for (int t = 0; t < 4; t++) {
                bf16x8 a = *(const bf16x8*)&S.msg[(mt * 16 + m) * 136 + t * 32 + ksub];
                acc0 = mfma16(a, bp1[t][0], acc0);
                acc1 = mfma16(a, bp1[t][1], acc1);
            }
            float p4[4];
            #pragma unroll
            for (int rr = 0; rr < 4; rr++)
                p4[rr] = fast_silu(acc0[rr] + pb1v[0]) * pw2v[0]
                       + fast_silu(acc1[rr] + pb1v[1]) * pw2v[1];
            #pragma unroll
            for (int mask = 1; mask < 16; mask <<= 1) {
                #pragma unroll
                for (int rr = 0; rr < 4; rr++) p4[rr] += __shfl_xor(p4[rr], mask);
            }
            if (m == 0) {
                #pragma unroll
                for (int rr = 0; rr < 4; rr++)
                    S.pcpart[w][mt * 16 + quad * 4 + rr] = p4[rr];
            }
        }
        // ---- agg: segment loop over receiver-sorted rows (uniform branches) ----
        {
            int half = tid >> 7, col = tid & 127;
            int r0 = half * 32;
            u32 bm32 = __builtin_amdgcn_readfirstlane((u32)(S.bmap >> r0)) & ~1u;
            float a = 0.f;
            int cur = S.rcvloc[r0];
            int rr = r0;
            const int end0 = r0 + 32;
            while (true) {
                int nb = bm32 ? (r0 + __builtin_ctz(bm32)) : end0;
                for (; rr < nb; ++rr) a += bf2f(S.msg[rr * 136 + col]);
                atomicAdd(&agg[(size_t)cur * 128 + col], a);
                if (nb == end0) break;
                a = 0.f;
                cur = S.rcvloc[nb];
                bm32 &= bm32 - 1;
            }
        }
        bar_lds();   // X5
        if (tid < 192) {
            int ee = tid / 3, c = tid - ee * 3;
            float pc = S.pcpart[0][ee] + S.pcpart[1][ee] + S.pcpart[2][ee] + S.pcpart[3][ee];
            float tr = S.diff[ee][c] * pc;
            tr = fminf(fmaxf(tr, -100.f), 100.f);
            atomicAdd(&posacc[S.sndloc[ee] * 3 + c], tr);
        }
    }
}

// Node MLP (+ fused pos output): h_new = h + (silu([h,agg]@nW1+nb1)@nW2+nb2)
__global__ __launch_bounds__(256, 4) void node_kernel(
    const u16* __restrict__ P, const float* __restrict__ h,
    const float* __restrict__ agg,
    const u16* __restrict__ nW1T, const float* __restrict__ nb1,
    const u16* __restrict__ nW2T, const float* __restrict__ nb2,
    const float* __restrict__ pos, const float* __restrict__ posacc,
    float* __restrict__ out)
{
    __shared__ alignas(16) u16 m1[64 * 136];
    const int tid  = threadIdx.x;
    const int w    = tid >> 6;
    const int lane = tid & 63;
    const int m    = lane & 15;
    const int quad = lane >> 4;
    const int ksub = quad * 8;

    bf16x8 bw1[4][2], bw2[4][2];
    float b1v[2], b2v[2];
    #pragma unroll
    for (int cc = 0; cc < 2; cc++) {
        int col = (2 * w + cc) * 16 + m;
        #pragma unroll
        for (int t = 0; t < 4; t++) {
            bw1[t][cc] = ld8(nW1T + col * 256 + 128 + t * 32 + ksub);  // agg rows of nW1
            bw2[t][cc] = ld8(nW2T + col * 128 + t * 32 + ksub);
        }
        b1v[cc] = nb1[col];
        b2v[cc] = nb2[col];
    }
    const int base = blockIdx.x * 64;
    #pragma unroll
    for (int mt = 0; mt < 4; mt++) {
        int nm = base + mt * 16 + m;
        if (nm >= NNODES) nm = NNODES - 1;
        f32x4 acc0 = (f32x4){0,0,0,0}, acc1 = (f32x4){0,0,0,0};
        #pragma unroll
        for (int t = 0; t < 4; t++) {
            const float* ap = agg + (size_t)nm * 128 + t * 32 + ksub;
            f32x4 lo = *(const f32x4*)ap;
            f32x4 hi = *(const f32x4*)(ap + 4);
            bf16x8 a;
            #pragma unroll
            for (int j = 0; j < 4; j++) {
                a[j]     = (short)f2bf(lo[j]);
                a[4 + j] = (short)f2bf(hi[j]);
            }
            acc0 = mfma16(a, bw1[t][0], acc0);
            acc1 = mfma16(a, bw1[t][1], acc1);
        }
        #pragma unroll
        for (int cc = 0; cc < 2; cc++) {
            f32x4 acc = cc ? acc1 : acc0;
            int col = (2 * w + cc) * 16 + m;
            #pragma unroll
            for (int rr = 0; rr < 4; rr++) {
                int row = mt * 16 + quad * 4 + rr;
                int nrc = base + row; if (nrc >= NNODES) nrc = NNODES - 1;
                float v = acc[rr] + bf2f(P[(size_t)nrc * 384 + 256 + col]) + b1v[cc];
                m1[row * 136 + col] = f2bf(fast_silu(v));
            }
        }
    }
    __syncthreads();
    #pragma unroll
    for (int mt = 0; mt < 4; mt++) {
        f32x4 acc0 = (f32x4){0,0,0,0}, acc1 = (f32x4){0,0,0,0};
        #pragma unroll
        for (int t = 0; t < 4; t++) {
            bf16x8 a = *(const bf16x8*)&m1[(mt * 16 + m) * 136 + t * 32 + ksub];
            acc0 = mfma16(a, bw2[t][0], acc0);
            acc1 = mfma16(a, bw2[t][1], acc1);
        }
        #pragma unroll
        for (int cc = 0; cc < 2; cc++) {
            f32x4 acc = cc ? acc1 : acc0;
            int col = (2 * w + cc) * 16 + m;
            #pragma unroll
            for (int rr = 0; rr < 4; rr++) {
                int nr = base + mt * 16 + quad * 4 + rr;
                if (nr < NNODES)
                    out[(size_t)nr * 128 + col] = acc[rr] + b2v[cc] + h[(size_t)nr * 128 + col];
            }
        }
    }
    // fused pos output: 192 elems per block covers 150144 >= 150000
    if (tid < 192) {
        int i = blockIdx.x * 192 + tid;
        if (i < NNODES * 3) out[NNODES * 128 + i] = pos[i] + posacc[i];
    }
}

extern "C" void kernel_launch(void* const* d_in, const int* in_sizes, int n_in,
                              void* d_out, int out_size, void* d_ws, size_t ws_size,
                              hipStream_t stream) {
    (void)in_sizes; (void)n_in; (void)out_size; (void)ws_size;
    const float* h   = (const float*)d_in[0];
    const float* pos = (const float*)d_in[1];
    const int*   snd = (const int*)d_in[2];
    const int*   rcv = (const int*)d_in[3];
    const float* eW1 = (const float*)d_in[4];
    const float* eb1 = (const float*)d_in[5];
    const float* eW2 = (const float*)d_in[6];
    const float* eb2 = (const float*)d_in[7];
    const float* nW1 = (const float*)d_in[8];
    const float* nb1 = (const float*)d_in[9];
    const float* nW2 = (const float*)d_in[10];
    const float* nb2 = (const float*)d_in[11];
    const float* pW1 = (const float*)d_in[12];
    const float* pb1 = (const float*)d_in[13];
    const float* pW2 = (const float*)d_in[14];
    float* out = (float*)d_out;

    float* agg    = (float*)d_ws;                       // [N,128] f32
    float* posacc = agg + (size_t)NNODES * 128;         // [N,3]
    u16* P    = (u16*)(posacc + (size_t)NNODES * 3);    // [N,384] bf16
    u16* eW1T = P + (size_t)NNODES * 384;               // [128][256]
    u16* eW2T = eW1T + 128 * 256;                       // [128][128]
    u16* pW1T = eW2T + 128 * 128;
    u16* nW1T = pW1T + 128 * 128;                       // [128][256]
    u16* nW2T = nW1T + 128 * 256;
    int* counts = (int*)(nW2T + 128 * 128);             // [50048]
    int* excl   = counts + 50048;
    int* blkSum = excl + 50048;                         // [256]
    int* blkOff = blkSum + 256;                         // [256]
    int* cursor = blkOff + 256;                         // [50048]
    int* perm   = cursor + 50048;                       // [E]

    hipMemsetAsync(agg, 0, (size_t)NNODES * 131 * sizeof(float), stream);
    hipMemsetAsync(counts, 0, 50048 * sizeof(int), stream);

    prep_kernel<<<TRN_BLOCKS + (NEDGES + 255) / 256, 256, 0, stream>>>(
        eW1, eW2, pW1, nW1, nW2, eW1T, eW2T, pW1T, nW1T, nW2T, rcv, counts);

    gemm_p<<<(NNODES + 63) / 64, 256, 0, stream>>>(h, eW1T, nW1T, eb1, P);

    scan1<<<SCAN_BLOCKS, 256, 0, stream>>>(counts, excl, blkSum);
    scan2<<<1, 256, 0, stream>>>(blkSum, blkOff);
    scan3<<<SCAN_BLOCKS, 256, 0, stream>>>(excl, blkOff, cursor);
    scatter_kernel<<<(NEDGES + 255) / 256, 256, 0, stream>>>(rcv, cursor, perm);

    edge_kernel<<<EB, 256, 0, stream>>>(
        P, pos, snd, rcv, perm,
        eW1 + 256 * 128,
        eW2T, eb2, pW1T, pb1, pW2,
        agg, posacc);

    node_kernel<<<(NNODES + 63) / 64, 256, 0, stream>>>(
        P, h, agg, nW1T, nb1, nW2T, nb2, pos, posacc, out);
}

// Round 2
// 454.871 us; speedup vs baseline: 1.2158x; 1.2158x over previous
//
#include <hip/hip_runtime.h>
#include <hip/hip_bf16.h>

#define NNODES 50000
#define NEDGES 800000
#define EB 1024          // edge grid: 4 blocks/CU resident, 128 blocks/XCD
#define SCAN_BLOCKS 196  // ceil(50000/256)
#define TRN_BLOCKS 448   // 114688 weight elems / 256

typedef short bf16x8 __attribute__((ext_vector_type(8)));
typedef float f32x4 __attribute__((ext_vector_type(4)));
typedef unsigned short u16;
typedef unsigned int u32;

__device__ __forceinline__ u16 f2bf(float f) {
    __hip_bfloat16 b = __float2bfloat16(f);
    return *reinterpret_cast<u16*>(&b);
}
__device__ __forceinline__ float bf2f(u16 v) {
    u32 u = ((u32)v) << 16;
    return __uint_as_float(u);
}
__device__ __forceinline__ u32 pack2(float a, float b) {
    __hip_bfloat162 t = __float22bfloat162_rn(float2{a, b});
    return *reinterpret_cast<u32*>(&t);
}
// silu without IEEE divide: x * rcp(1 + 2^(-x*log2e))
__device__ __forceinline__ float fast_silu(float x) {
    float e = __builtin_amdgcn_exp2f(-1.442695040888963f * x);
    return x * __builtin_amdgcn_rcpf(1.0f + e);
}
__device__ __forceinline__ bf16x8 ld8(const u16* p) {
    return *(const bf16x8*)p;
}
__device__ __forceinline__ f32x4 mfma16(bf16x8 a, bf16x8 b, f32x4 c) {
    return __builtin_amdgcn_mfma_f32_16x16x32_bf16(a, b, c, 0, 0, 0);
}
// Barrier that drains LDS ops only — does NOT wait for vector-memory ops
// (prefetch loads and in-flight atomics). Safe: the only global writes in
// edge_kernel are atomics nobody re-reads in-kernel, and all global->VGPR
// loads get compiler-inserted vmcnt waits at their use sites.
__device__ __forceinline__ void bar_lds() {
    asm volatile("s_waitcnt lgkmcnt(0)\n\ts_barrier" ::: "memory");
}

// ---- prep: 5 weight transposes (fp32->bf16) + receiver histogram ----
__global__ void prep_kernel(const float* __restrict__ eW1, const float* __restrict__ eW2,
                            const float* __restrict__ pW1, const float* __restrict__ nW1,
                            const float* __restrict__ nW2,
                            u16* __restrict__ eW1T, u16* __restrict__ eW2T,
                            u16* __restrict__ pW1T, u16* __restrict__ nW1T,
                            u16* __restrict__ nW2T,
                            const int* __restrict__ rcv, int* __restrict__ counts) {
    int b = blockIdx.x;
    if (b < TRN_BLOCKS) {
        int i = b * 256 + threadIdx.x;
        const float* src; u16* dst; int K;
        if (i < 32768)      { src = eW1; dst = eW1T; K = 256; }
        else if (i < 49152) { src = eW2; dst = eW2T; K = 128; i -= 32768; }
        else if (i < 65536) { src = pW1; dst = pW1T; K = 128; i -= 49152; }
        else if (i < 98304) { src = nW1; dst = nW1T; K = 256; i -= 65536; }
        else                { src = nW2; dst = nW2T; K = 128; i -= 98304; }
        int n = i / K, k = i - n * K;
        dst[i] = f2bf(src[k * 128 + n]);
    } else {
        int e = (b - TRN_BLOCKS) * 256 + threadIdx.x;
        if (e < NEDGES) atomicAdd(&counts[rcv[e]], 1);
    }
}

// ---- P precompute: P[n] = [h@eW1a + eb1/2 | h@eW1b + eb1/2 | h@nW1a] (bf16) ----
__global__ __launch_bounds__(256) void gemm_p(
    const float* __restrict__ h, const u16* __restrict__ eW1T,
    const u16* __restrict__ nW1T, const float* __restrict__ eb1,
    u16* __restrict__ P)
{
    const int tid  = threadIdx.x;
    const int w    = tid >> 6;
    const int lane = tid & 63;
    const int m    = lane & 15;
    const int quad = lane >> 4;
    const int ksub = quad * 8;

    bf16x8 bw[4][6];
    float bias[6];
    #pragma unroll
    for (int cc = 0; cc < 6; cc++) {
        int C = 96 * w + 16 * cc + m;
        const u16* bp;
        if (C < 128)      { bp = eW1T + C * 256;               bias[cc] = 0.5f * eb1[C]; }
        else if (C < 256) { bp = eW1T + (C - 128) * 256 + 128; bias[cc] = 0.5f * eb1[C - 128]; }
        else              { bp = nW1T + (C - 256) * 256;       bias[cc] = 0.f; }
        #pragma unroll
        for (int t = 0; t < 4; t++) bw[t][cc] = ld8(bp + t * 32 + ksub);
    }
    const int base = blockIdx.x * 64;
    #pragma unroll
    for (int mt = 0; mt < 4; mt++) {
        int nm = base + mt * 16 + m;
        if (nm >= NNODES) nm = NNODES - 1;
        bf16x8 afr[4];
        #pragma unroll
        for (int t = 0; t < 4; t++) {
            const float* ap = h + (size_t)nm * 128 + t * 32 + ksub;
            f32x4 lo = *(const f32x4*)ap;
            f32x4 hi = *(const f32x4*)(ap + 4);
            #pragma unroll
            for (int j = 0; j < 4; j++) {
                afr[t][j]     = (short)f2bf(lo[j]);
                afr[t][4 + j] = (short)f2bf(hi[j]);
            }
        }
        f32x4 acc[6];
        #pragma unroll
        for (int cc = 0; cc < 6; cc++) acc[cc] = (f32x4){0,0,0,0};
        #pragma unroll
        for (int t = 0; t < 4; t++)
            #pragma unroll
            for (int cc = 0; cc < 6; cc++)
                acc[cc] = mfma16(afr[t], bw[t][cc], acc[cc]);
        #pragma unroll
        for (int cc = 0; cc < 6; cc++) {
            int C = 96 * w + 16 * cc + m;
            #pragma unroll
            for (int r = 0; r < 4; r++) {
                int nr = base + mt * 16 + quad * 4 + r;
                if (nr < NNODES) P[(size_t)nr * 384 + C] = f2bf(acc[cc][r] + bias[cc]);
            }
        }
    }
}

// ---- scan chain ----
__global__ void scan1(const int* __restrict__ counts, int* __restrict__ excl,
                      int* __restrict__ blkSum) {
    __shared__ int tmp[256];
    int tx = threadIdx.x;
    int i = blockIdx.x * 256 + tx;
    int v = (i < NNODES) ? counts[i] : 0;
    tmp[tx] = v;
    __syncthreads();
    for (int off = 1; off < 256; off <<= 1) {
        int t = (tx >= off) ? tmp[tx - off] : 0;
        __syncthreads();
        tmp[tx] += t;
        __syncthreads();
    }
    if (i < NNODES) excl[i] = tmp[tx] - v;
    if (tx == 255) blkSum[blockIdx.x] = tmp[255];
}
__global__ void scan2(const int* __restrict__ blkSum, int* __restrict__ blkOff) {
    __shared__ int tmp[256];
    int tx = threadIdx.x;
    int v = (tx < SCAN_BLOCKS) ? blkSum[tx] : 0;
    tmp[tx] = v;
    __syncthreads();
    for (int off = 1; off < 256; off <<= 1) {
        int t = (tx >= off) ? tmp[tx - off] : 0;
        __syncthreads();
        tmp[tx] += t;
        __syncthreads();
    }
    if (tx < SCAN_BLOCKS) blkOff[tx] = tmp[tx] - v;
}
__global__ void scan3(const int* __restrict__ excl, const int* __restrict__ blkOff,
                      int* __restrict__ cursor) {
    int i = blockIdx.x * 256 + threadIdx.x;
    if (i < NNODES) cursor[i] = excl[i] + blkOff[blockIdx.x];
}
__global__ void scatter_kernel(const int* __restrict__ rcv, int* __restrict__ cursor,
                               int* __restrict__ perm) {
    int e = blockIdx.x * 256 + threadIdx.x;
    if (e < NEDGES) {
        int p = atomicAdd(&cursor[rcv[e]], 1);
        perm[p] = e;
    }
}

struct __align__(16) EdgeLds {
    u16   m1[64 * 136];       // XOR-swizzled 8-col chunks
    u16   msg[64 * 136];
    float diff[64][4];
    float pcpart[4][64];
    float wlast[128];
    int   sndloc[64];
    int   rcvloc[64];
    unsigned long long bmap;  // bit i = (rcv[i] != rcv[i-1]) within tile
};   // ~38 KB -> 4 blocks/CU

__global__ __launch_bounds__(256, 4) void edge_kernel(
    const u16* __restrict__ P, const float* __restrict__ pos,
    const int* __restrict__ snd, const int* __restrict__ rcv,
    const int* __restrict__ perm,
    const float* __restrict__ eW1last,
    const u16* __restrict__ eW2T, const float* __restrict__ eb2,
    const u16* __restrict__ pW1T, const float* __restrict__ pb1,
    const float* __restrict__ pW2,
    float* __restrict__ agg, float* __restrict__ posacc)
{
    __shared__ EdgeLds S;
    const int tid  = threadIdx.x;
    const int w    = tid >> 6;
    const int lane = tid & 63;
    const int m    = lane & 15;
    const int quad = lane >> 4;
    const int ksub = quad * 8;

    bf16x8 bw2[4][2], bp1[4][2];
    float b2v[2], pb1v[2], pw2v[2];
    #pragma unroll
    for (int cc = 0; cc < 2; cc++) {
        int col = (2 * w + cc) * 16 + m;
        #pragma unroll
        for (int t = 0; t < 4; t++) {
            bw2[t][cc] = ld8(eW2T + col * 128 + t * 32 + ksub);
            bp1[t][cc] = ld8(pW1T + col * 128 + t * 32 + ksub);
        }
        b2v[cc]  = eb2[col];
        pb1v[cc] = pb1[col];
        pw2v[cc] = pW2[col];
    }
    if (tid < 128) S.wlast[tid] = eW1last[tid];

    // XCD-chunked tile mapping: blocks of one XCD (blockIdx%8) own a
    // contiguous range of receiver-sorted tiles -> Pb gather + agg atomics
    // stay in that XCD's L2 (1.6MB + 3.2MB working set vs 4MB).
    const int NT  = NEDGES / 64;                 // 12500 (exact)
    const int xcd = blockIdx.x & 7;
    const int ib  = blockIdx.x >> 3;             // 0..127 within XCD
    const int per = (NT + 7) / 8;                // 1563
    const int t0  = xcd * per;
    const int t1  = (t0 + per < NT) ? t0 + per : NT;

    // 1-tile-deep prefetch of edge ids (3 VGPRs — NO P/pos prefetch; the
    // 40-reg version spilled to scratch and doubled FETCH_SIZE)
    int eg_n = 0, s_n = 0, r_n = 0;
    if (t0 + ib < t1) {
        eg_n = perm[(t0 + ib) * 64 + lane];
        s_n = snd[eg_n]; r_n = rcv[eg_n];
    }

    for (int t = t0 + ib; t < t1; t += 128) {
        const int s = s_n, r = r_n;
        const int tn = t + 128;
        const int tp = (tn < t1) ? tn : t;       // last iter: dummy (discarded)
        // prefetch stage 1: next tile's perm entries (independent)
        int eg2 = perm[tp * 64 + lane];

        // pos gather + radial in registers (all 256 threads, 4x redundant,
        // L1/L2-cached; removes the old S.radial round-trip + one barrier)
        float d0 = pos[s * 3 + 0] - pos[r * 3 + 0];
        float d1 = pos[s * 3 + 1] - pos[r * 3 + 1];
        float d2 = pos[s * 3 + 2] - pos[r * 3 + 2];
        float rad = d0 * d0 + d1 * d1 + d2 * d2;

        bar_lds();   // X1: previous tile's consumers of S.* are done
        if (tid < 64) {
            S.sndloc[tid] = s; S.rcvloc[tid] = r;
            S.diff[tid][0] = d0; S.diff[tid][1] = d1; S.diff[tid][2] = d2;
            int pv = __shfl_up(r, 1);
            unsigned long long bm = __ballot(lane > 0 && r != pv);
            if (tid == 0) S.bmap = bm;
        }
        // ---- layer1: m1 = silu(Pa[s] + Pb[r] + rad*wlast)  (bias pre-folded) ----
        {
            const int sw = lane >> 3;
            const u16* pa = P + (size_t)s * 384 + w * 32;
            const u16* pb = P + (size_t)r * 384 + 128 + w * 32;
            #pragma unroll
            for (int k = 0; k < 4; k++) {
                bf16x8 va = ld8(pa + k * 8);
                bf16x8 vb = ld8(pb + k * 8);
                u32 pk[4];
                #pragma unroll
                for (int jj = 0; jj < 4; jj++) {
                    int col = w * 32 + k * 8 + jj * 2;
                    float2 wl = *(const float2*)&S.wlast[col];
                    float v0 = bf2f((u16)va[jj * 2])     + bf2f((u16)vb[jj * 2])     + rad * wl.x;
                    float v1 = bf2f((u16)va[jj * 2 + 1]) + bf2f((u16)vb[jj * 2 + 1]) + rad * wl.y;
                    pk[jj] = pack2(fast_silu(v0), fast_silu(v1));
                }
                int chunk = (w * 4 + k) ^ sw;
                *(uint4*)&S.m1[lane * 136 + chunk * 8] =
                    make_uint4(pk[0], pk[1], pk[2], pk[3]);
            }
        }
        // prefetch stage 2: next snd/rcv (eg2 landed during layer1)
        s_n = snd[eg2]; r_n = rcv[eg2]; eg_n = eg2;

        bar_lds();   // X2: m1 ready
        // ---- layer2: msg = silu(m1 @ eW2 + b2) ----
        #pragma unroll
        for (int mt = 0; mt < 4; mt++) {
            const int rs = mt * 2 + (m >> 3);
            const int row = mt * 16 + m;
            f32x4 acc0 = (f32x4){0,0,0,0}, acc1 = (f32x4){0,0,0,0};
            #pragma unroll
            for (int t4 = 0; t4 < 4; t4++) {
                bf16x8 a = *(const bf16x8*)&S.m1[row * 136 + ((t4 * 4 + quad) ^ rs) * 8];
                acc0 = mfma16(a, bw2[t4][0], acc0);
                acc1 = mfma16(a, bw2[t4][1], acc1);
            }
            #pragma unroll
            for (int cc = 0; cc < 2; cc++) {
                f32x4 acc = cc ? acc1 : acc0;
                int col = (2 * w + cc) * 16 + m;
                #pragma unroll
                for (int rr = 0; rr < 4; rr++) {
                    int orow = mt * 16 + quad * 4 + rr;
                    S.msg[orow * 136 + col] = f2bf(fast_silu(acc[rr] + b2v[cc]));
                }
            }
        }
        bar_lds();   // X3: msg ready
        // ---- pos head: pc = silu(msg @ pW1 + pb1) @ pW2 (per-wave partials) ----
        #pragma unroll
        for (int mt = 0; mt < 4; mt++) {
            f32x4 acc0 = (f32x4){0,0,0,0}, acc1 = (f32x4){0,0,0,0};
            #pragma unroll
            for (int t4 = 0; t4 < 4; t4++) {
                bf16x8 a = *(const bf16x8*)&S.msg[(mt * 16 + m) * 136 + t4 * 32 + ksub];
                acc0 = mfma16(a, bp1[t4][0], acc0);
                acc1 = mfma16(a, bp1[t4][1], acc1);
            }
            float p4[4];
            #pragma unroll
            for (int rr = 0; rr < 4; rr++)
                p4[rr] = fast_silu(acc0[rr] + pb1v[0]) * pw2v[0]
                       + fast_silu(acc1[rr] + pb1v[1]) * pw2v[1];
            #pragma unroll
            for (int mask = 1; mask < 16; mask <<= 1) {
                #pragma unroll
                for (int rr = 0; rr < 4; rr++) p4[rr] += __shfl_xor(p4[rr], mask);
            }
            if (m == 0) {
                #pragma unroll
                for (int rr = 0; rr < 4; rr++)
                    S.pcpart[w][mt * 16 + quad * 4 + rr] = p4[rr];
            }
        }
        // ---- agg: uniform segment loop over receiver-sorted rows ----
        {
            int half = tid >> 7, col = tid & 127;
            int r0 = half * 32;
            u32 bm32 = __builtin_amdgcn_readfirstlane((u32)(S.bmap >> r0)) & ~1u;
            float a = 0.f;
            int cur = S.rcvloc[r0];
            int rr = r0;
            const int end0 = r0 + 32;
            while (true) {
                int nb = bm32 ? (r0 + __builtin_ctz(bm32)) : end0;
                for (; rr < nb; ++rr) a += bf2f(S.msg[rr * 136 + col]);
                atomicAdd(&agg[(size_t)cur * 128 + col], a);
                if (nb == end0) break;
                a = 0.f;
                cur = S.rcvloc[nb];
                bm32 &= bm32 - 1;
            }
        }
        bar_lds();   // X4: pcpart ready, msg fully consumed
        if (tid < 192) {
            int ee = tid / 3, c = tid - ee * 3;
            float pc = S.pcpart[0][ee] + S.pcpart[1][ee] + S.pcpart[2][ee] + S.pcpart[3][ee];
            float tr = S.diff[ee][c] * pc;
            tr = fminf(fmaxf(tr, -100.f), 100.f);
            atomicAdd(&posacc[S.sndloc[ee] * 3 + c], tr);
        }
    }
}

// Node MLP (+ fused pos output): h_new = h + (silu([h,agg]@nW1+nb1)@nW2+nb2)
__global__ __launch_bounds__(256, 4) void node_kernel(
    const u16* __restrict__ P, const float* __restrict__ h,
    const float* __restrict__ agg,
    const u16* __restrict__ nW1T, const float* __restrict__ nb1,
    const u16* __restrict__ nW2T, const float* __restrict__ nb2,
    const float* __restrict__ pos, const float* __restrict__ posacc,
    float* __restrict__ out)
{
    __shared__ alignas(16) u16 m1[64 * 136];
    const int tid  = threadIdx.x;
    const int w    = tid >> 6;
    const int lane = tid & 63;
    const int m    = lane & 15;
    const int quad = lane >> 4;
    const int ksub = quad * 8;

    bf16x8 bw1[4][2], bw2[4][2];
    float b1v[2], b2v[2];
    #pragma unroll
    for (int cc = 0; cc < 2; cc++) {
        int col = (2 * w + cc) * 16 + m;
        #pragma unroll
        for (int t = 0; t < 4; t++) {
            bw1[t][cc] = ld8(nW1T + col * 256 + 128 + t * 32 + ksub);  // agg rows of nW1
            bw2[t][cc] = ld8(nW2T + col * 128 + t * 32 + ksub);
        }
        b1v[cc] = nb1[col];
        b2v[cc] = nb2[col];
    }
    const int base = blockIdx.x * 64;
    #pragma unroll
    for (int mt = 0; mt < 4; mt++) {
        int nm = base + mt * 16 + m;
        if (nm >= NNODES) nm = NNODES - 1;
        f32x4 acc0 = (f32x4){0,0,0,0}, acc1 = (f32x4){0,0,0,0};
        #pragma unroll
        for (int t = 0; t < 4; t++) {
            const float* ap = agg + (size_t)nm * 128 + t * 32 + ksub;
            f32x4 lo = *(const f32x4*)ap;
            f32x4 hi = *(const f32x4*)(ap + 4);
            bf16x8 a;
            #pragma unroll
            for (int j = 0; j < 4; j++) {
                a[j]     = (short)f2bf(lo[j]);
                a[4 + j] = (short)f2bf(hi[j]);
            }
            acc0 = mfma16(a, bw1[t][0], acc0);
            acc1 = mfma16(a, bw1[t][1], acc1);
        }
        #pragma unroll
        for (int cc = 0; cc < 2; cc++) {
            f32x4 acc = cc ? acc1 : acc0;
            int col = (2 * w + cc) * 16 + m;
            #pragma unroll
            for (int rr = 0; rr < 4; rr++) {
                int row = mt * 16 + quad * 4 + rr;
                int nrc = base + row; if (nrc >= NNODES) nrc = NNODES - 1;
                float v = acc[rr] + bf2f(P[(size_t)nrc * 384 + 256 + col]) + b1v[cc];
                m1[row * 136 + col] = f2bf(fast_silu(v));
            }
        }
    }
    __syncthreads();
    #pragma unroll
    for (int mt = 0; mt < 4; mt++) {
        f32x4 acc0 = (f32x4){0,0,0,0}, acc1 = (f32x4){0,0,0,0};
        #pragma unroll
        for (int t = 0; t < 4; t++) {
            bf16x8 a = *(const bf16x8*)&m1[(mt * 16 + m) * 136 + t * 32 + ksub];
            acc0 = mfma16(a, bw2[t][0], acc0);
            acc1 = mfma16(a, bw2[t][1], acc1);
        }
        #pragma unroll
        for (int cc = 0; cc < 2; cc++) {
            f32x4 acc = cc ? acc1 : acc0;
            int col = (2 * w + cc) * 16 + m;
            #pragma unroll
            for (int rr = 0; rr < 4; rr++) {
                int nr = base + mt * 16 + quad * 4 + rr;
                if (nr < NNODES)
                    out[(size_t)nr * 128 + col] = acc[rr] + b2v[cc] + h[(size_t)nr * 128 + col];
            }
        }
    }
    // fused pos output: 192 elems per block covers 150144 >= 150000
    if (tid < 192) {
        int i = blockIdx.x * 192 + tid;
        if (i < NNODES * 3) out[NNODES * 128 + i] = pos[i] + posacc[i];
    }
}

extern "C" void kernel_launch(void* const* d_in, const int* in_sizes, int n_in,
                              void* d_out, int out_size, void* d_ws, size_t ws_size,
                              hipStream_t stream) {
    (void)in_sizes; (void)n_in; (void)out_size; (void)ws_size;
    const float* h   = (const float*)d_in[0];
    const float* pos = (const float*)d_in[1];
    const int*   snd = (const int*)d_in[2];
    const int*   rcv = (const int*)d_in[3];
    const float* eW1 = (const float*)d_in[4];
    const float* eb1 = (const float*)d_in[5];
    const float* eW2 = (const float*)d_in[6];
    const float* eb2 = (const float*)d_in[7];
    const float* nW1 = (const float*)d_in[8];
    const float* nb1 = (const float*)d_in[9];
    const float* nW2 = (const float*)d_in[10];
    const float* nb2 = (const float*)d_in[11];
    const float* pW1 = (const float*)d_in[12];
    const float* pb1 = (const float*)d_in[13];
    const float* pW2 = (const float*)d_in[14];
    float* out = (float*)d_out;

    float* agg    = (float*)d_ws;                       // [N,128] f32
    float* posacc = agg + (size_t)NNODES * 128;         // [N,3]
    u16* P    = (u16*)(posacc + (size_t)NNODES * 3);    // [N,384] bf16
    u16* eW1T = P + (size_t)NNODES * 384;               // [128][256]
    u16* eW2T = eW1T + 128 * 256;                       // [128][128]
    u16* pW1T = eW2T + 128 * 128;
    u16* nW1T = pW1T + 128 * 128;                       // [128][256]
    u16* nW2T = nW1T + 128 * 256;
    int* counts = (int*)(nW2T + 128 * 128);             // [50048]
    int* excl   = counts + 50048;
    int* blkSum = excl + 50048;                         // [256]
    int* blkOff = blkSum + 256;                         // [256]
    int* cursor = blkOff + 256;                         // [50048]
    int* perm   = cursor + 50048;                       // [E]

    hipMemsetAsync(agg, 0, (size_t)NNODES * 131 * sizeof(float), stream);
    hipMemsetAsync(counts, 0, 50048 * sizeof(int), stream);

    prep_kernel<<<TRN_BLOCKS + (NEDGES + 255) / 256, 256, 0, stream>>>(
        eW1, eW2, pW1, nW1, nW2, eW1T, eW2T, pW1T, nW1T, nW2T, rcv, counts);

    gemm_p<<<(NNODES + 63) / 64, 256, 0, stream>>>(h, eW1T, nW1T, eb1, P);

    scan1<<<SCAN_BLOCKS, 256, 0, stream>>>(counts, excl, blkSum);
    scan2<<<1, 256, 0, stream>>>(blkSum, blkOff);
    scan3<<<SCAN_BLOCKS, 256, 0, stream>>>(excl, blkOff, cursor);
    scatter_kernel<<<(NEDGES + 255) / 256, 256, 0, stream>>>(rcv, cursor, perm);

    edge_kernel<<<EB, 256, 0, stream>>>(
        P, pos, snd, rcv, perm,
        eW1 + 256 * 128,
        eW2T, eb2, pW1T, pb1, pW2,
        agg, posacc);

    node_kernel<<<(NNODES + 63) / 64, 256, 0, stream>>>(
        P, h, agg, nW1T, nb1, nW2T, nb2, pos, posacc, out);
}